// Round 10
// baseline (266.077 us; speedup 1.0000x reference)
//
#include <hip/hip_runtime.h>
#include <stdint.h>
#include <stddef.h>

#define SEQ   2048
#define NH    16
#define DH    64
#define DM    1024
#define NTOK  8192   // B*T = 4*2048

typedef unsigned short u16;
typedef unsigned int u32;
typedef short bf16x8 __attribute__((ext_vector_type(8)));
typedef short bf16x4 __attribute__((ext_vector_type(4)));
typedef float f32x4  __attribute__((ext_vector_type(4)));
typedef unsigned short u16x4 __attribute__((ext_vector_type(4)));
typedef unsigned short u16x8 __attribute__((ext_vector_type(8)));
typedef unsigned int u32x4 __attribute__((ext_vector_type(4)));

// 0.125 (1/sqrt(Dh)) * log2(e): folded into Q so softmax uses bare exp2
#define QSCALE 0.18033688011112042f

// s_waitcnt immediates: vmcnt[3:0] | expcnt<<4 | lgkmcnt<<8 | vmcnt[5:4]<<14
#define WAIT_VM6  0x0F76  // vmcnt(6)
#define WAIT_VM2  0x0F72  // vmcnt(2)
#define WAIT_VM0  0x0F70  // vmcnt(0)

// round-to-nearest-even fp32 -> bf16 bits
__device__ __forceinline__ u16 f2bf(float f) {
  union { float f; unsigned u; } v; v.f = f;
  return (u16)((v.u + 0x7FFFu + ((v.u >> 16) & 1u)) >> 16);
}

// async global->LDS, 16B per lane (dest = wave-uniform base + lane*16)
__device__ __forceinline__ void gload_lds16(const void* g, void* l) {
  __builtin_amdgcn_global_load_lds(
      (const __attribute__((address_space(1))) void*)g,
      (__attribute__((address_space(3))) void*)l, 16, 0, 0);
}

__device__ __forceinline__ bf16x8 cat44(bf16x4 a, bf16x4 b) {
  bf16x8 r;
  r[0] = a[0]; r[1] = a[1]; r[2] = a[2]; r[3] = a[3];
  r[4] = b[0]; r[5] = b[1]; r[6] = b[2]; r[7] = b[3];
  return r;
}

__global__ __launch_bounds__(256) void cast_kernel(const float* __restrict__ src,
                                                   u16* __restrict__ dst, int n4) {
  int i = blockIdx.x * 256 + threadIdx.x;
  if (i < n4) {
    const float4 f = ((const float4*)src)[i];
    u16x4 o;
    o.x = f2bf(f.x); o.y = f2bf(f.y); o.z = f2bf(f.z); o.w = f2bf(f.w);
    ((u16x4*)dst)[i] = o;
  }
}

// Fused cast + fragment-major pack of weight W [N,K=1024] fp32 (row-major).
// Bp organized in 1KB blocks, block id = c*NS + s  (c = k>>5 chunk, s = n>>4
// subtile, NS = N/16). Within a block, lane l = quad*16+l16 holds the 8 bf16
// W[s*16+l16][c*32+quad*8 .. +7] — exactly the per-lane MFMA B-fragment.
__global__ __launch_bounds__(256) void pack_b(const float* __restrict__ W,
                                              u16* __restrict__ Bp, int NS) {
  const int chunk = blockIdx.x * 256 + threadIdx.x;
  const int lane = chunk & 63, blk = chunk >> 6;
  const int c = blk / NS, s = blk % NS;
  const int n = s * 16 + (lane & 15);
  const int k0 = c * 32 + (lane >> 4) * 8;
  const float4 f0 = *(const float4*)&W[(size_t)n * DM + k0];
  const float4 f1 = *(const float4*)&W[(size_t)n * DM + k0 + 4];
  u16x8 o;
  o[0] = f2bf(f0.x); o[1] = f2bf(f0.y); o[2] = f2bf(f0.z); o[3] = f2bf(f0.w);
  o[4] = f2bf(f1.x); o[5] = f2bf(f1.y); o[6] = f2bf(f1.z); o[7] = f2bf(f1.w);
  *(u16x8*)&Bp[(size_t)chunk * 8] = o;
}

// C[M,N] = A[M,1024] * B[N,1024]^T, B pre-packed fragment-major (see pack_b).
// 256x128 tile, BK=64, 8 waves (4M x 2N of 64x64 each), 512 threads.
// Deep-pipeline structure (the regime the 2-phase class can't reach):
//  - BOTH operands staged through LDS via gload_lds: A 32KB (XOR-swizzled,
//    same verified pattern as before), B 16KB (pre-packed 1KB fragment blocks
//    staged linearly -> conflict-free b128 reads). No B register buffer:
//    ~64 VGPR freed vs the streaming version.
//  - TRI-buffered LDS (3 x 48KB = 144KB, 1 block/CU): prefetch distance =
//    2 K-steps. vmcnt(6) at step end drains only the PREVIOUS step's 6 loads
//    (4 A + 2 B per wave); this step's 6 stay in flight across the barrier —
//    the counted-vmcnt discipline, never draining to distance 1.
//  - One barrier/step, setprio(1) around the 32-MFMA block, read-ahead source
//    order (compiler emits fine-grained lgkmcnt for ds_read->MFMA).
// Grids are exact machine rounds at 1 block/CU: gemm0 768 = 3, gemm1 256 = 1.
// XCD-chunked blockIdx swizzle (T1) as verified in round 6.
#define GA_SZ (256 * 64)   // u16 per A buffer (32KB)
#define GB_SZ (128 * 64)   // u16 per B buffer (16KB)
template <int EPI>
__global__ __launch_bounds__(512, 2) void gemm_deep(
    const u16* __restrict__ A, const u16* __restrict__ Bp, int NS, int N_,
    u16* __restrict__ Qo, u16* __restrict__ Ko, u16* __restrict__ Vto,
    float* __restrict__ Co) {
  __shared__ __align__(16) u16 sA[3][GA_SZ];
  __shared__ __align__(16) u16 sB[3][GB_SZ];
  const int tid = threadIdx.x;
  const int wave = tid >> 6, lane = tid & 63;
  const int l16 = lane & 15, quad = lane >> 4;
  const int sw = l16 & 7;
  const int wm = (wave >> 1) * 64, wn = (wave & 1) * 64;
  // XCD swizzle: bijective for nwg % 8 == 0 (768 and 256 here)
  const int nbx = (int)gridDim.x;
  const int id = (int)(blockIdx.y * nbx + blockIdx.x);
  const int cpx = (int)(gridDim.x * gridDim.y) >> 3;
  const int wid = (id & 7) * cpx + (id >> 3);
  const int row0 = (wid / nbx) * 256, col0 = (wid % nbx) * 128;
  const int ck0 = ((quad ^ sw) << 3);
  const int ck1 = (((quad + 4) ^ sw) << 3);
  const int scol0 = col0 >> 4;              // first n-subtile of this block
  const int fb0 = wave * 2;                 // B fragment-blocks staged by this wave
  const int kkA = fb0 >> 3, sA_ = fb0 & 7;  // decode for fb0 (fb0+1 same kk, s+1)

  f32x4 acc[4][4];
  for (int a = 0; a < 4; ++a)
    for (int b = 0; b < 4; ++b) acc[a][b] = (f32x4){0.f, 0.f, 0.f, 0.f};

  // stage K-step kt into buffers dA/dB: 4 A-gloads + 2 B-gloads per thread/wave
#define STAGE(kt, dA, dB)                                                      \
  do {                                                                         \
    for (int j = 0; j < 4; ++j) {                                              \
      const int li = j * 512 + tid;                                            \
      const int r = li >> 3;                                                   \
      const int cs = (((li & 7) ^ (r & 7)) << 3);                              \
      gload_lds16(A + (size_t)(row0 + r) * DM + ((kt) << 6) + cs,              \
                  (char*)(dA) + li * 16);                                      \
    }                                                                          \
    gload_lds16(Bp + ((size_t)((kt) * 2 + kkA) * NS + scol0 + sA_) * 512 +     \
                    lane * 8,                                                  \
                (char*)(dB) + fb0 * 1024);                                     \
    gload_lds16(Bp + ((size_t)((kt) * 2 + kkA) * NS + scol0 + sA_ + 1) * 512 + \
                    lane * 8,                                                  \
                (char*)(dB) + (fb0 + 1) * 1024);                               \
  } while (0)

  // prologue: stage k-steps 0 and 1
  STAGE(0, sA[0], sB[0]);
  STAGE(1, sA[1], sB[1]);
  __builtin_amdgcn_s_waitcnt(WAIT_VM6);  // step-0 buffers complete
  __builtin_amdgcn_s_barrier();

  int cur = 0;
  for (int t = 0; t < 16; ++t) {
    const int tn = (t + 2) & 15;               // wrap: last 2 iters re-stage k=0,1
    int pre = cur + 2; if (pre >= 3) pre -= 3;
    STAGE(tn, sA[pre], sB[pre]);
    const u16* sa = sA[cur];
    const u16* sb = sB[cur];
    // read-ahead all 16 fragments; compiler interleaves lgkmcnt with MFMA
    bf16x8 af0[4], af1[4], bf0[4], bf1[4];
    for (int mi = 0; mi < 4; ++mi)
      af0[mi] = *(const bf16x8*)&sa[(wm + mi * 16 + l16) * 64 + ck0];
    for (int ni = 0; ni < 4; ++ni)
      bf0[ni] = *(const bf16x8*)&sb[(((wn >> 4) + ni) * 512) + lane * 8];
    for (int mi = 0; mi < 4; ++mi)
      af1[mi] = *(const bf16x8*)&sa[(wm + mi * 16 + l16) * 64 + ck1];
    for (int ni = 0; ni < 4; ++ni)
      bf1[ni] = *(const bf16x8*)&sb[((8 + (wn >> 4) + ni) * 512) + lane * 8];
    __builtin_amdgcn_s_setprio(1);
    for (int mi = 0; mi < 4; ++mi)
      for (int ni = 0; ni < 4; ++ni)
        acc[mi][ni] = __builtin_amdgcn_mfma_f32_16x16x32_bf16(
            af0[mi], bf0[ni], acc[mi][ni], 0, 0, 0);
    for (int mi = 0; mi < 4; ++mi)
      for (int ni = 0; ni < 4; ++ni)
        acc[mi][ni] = __builtin_amdgcn_mfma_f32_16x16x32_bf16(
            af1[mi], bf1[ni], acc[mi][ni], 0, 0, 0);
    __builtin_amdgcn_s_setprio(0);
    __builtin_amdgcn_s_waitcnt(WAIT_VM6);  // (t+1)'s 6 loads done; (t+2)'s in flight
    __builtin_amdgcn_s_barrier();
    cur = cur + 1 == 3 ? 0 : cur + 1;
  }
  __builtin_amdgcn_s_waitcnt(WAIT_VM0);  // drain dangling wrap stages before exit
#undef STAGE

  // C/D layout: col = lane&15, row = quad*4 + reg
  if (EPI == 0) {
    const int which = col0 >> 10;  // 0:Q 1:K 2:V — uniform per block
    for (int mi = 0; mi < 4; ++mi)
      for (int ni = 0; ni < 4; ++ni) {
        const int rowb = row0 + wm + mi * 16 + quad * 4;
        const int col = col0 + wn + ni * 16 + l16;
        const int b = rowb >> 11, t = rowb & (SEQ - 1);
        const int c = col & (DM - 1);
        const int h = c >> 6, d = c & 63;
        const size_t bh = (size_t)b * NH + h;
        if (which == 2) {
          u16x4 pk;
          pk.x = f2bf(acc[mi][ni][0]); pk.y = f2bf(acc[mi][ni][1]);
          pk.z = f2bf(acc[mi][ni][2]); pk.w = f2bf(acc[mi][ni][3]);
          *(u16x4*)&Vto[(bh * DH + d) * SEQ + t] = pk;
        } else {
          for (int r = 0; r < 4; ++r) {
            const float v = acc[mi][ni][r];
            if (which == 0) Qo[(bh * SEQ + t + r) * DH + d] = f2bf(v * QSCALE);
            else            Ko[(bh * SEQ + t + r) * DH + d] = f2bf(v);
          }
        }
      }
  } else {
    for (int mi = 0; mi < 4; ++mi)
      for (int ni = 0; ni < 4; ++ni)
        for (int r = 0; r < 4; ++r) {
          const int row = row0 + wm + mi * 16 + quad * 4 + r;
          const int col = col0 + wn + ni * 16 + l16;
          Co[(size_t)row * N_ + col] = acc[mi][ni][r];
        }
  }
}

// Flash attention, non-causal, fixed max=0. 256 q/block, 8 waves x 32 q/wave
// (512 threads), dbuf K/V staging, S^T = K.Q^T, P @ ones row-sums, raw
// v_exp_f32, setprio(1) around MFMA clusters (T5). Grid: (T/256, B*H).
// XCD-chunked swizzle (round-6: FETCH 143 -> 25 MB, K/V L2-resident).
// In-register P via permuted-k PV fragments (round-9: equal perf to sP at the
// grid-capped 2 blocks/CU, fewer LDS ops, 32KB LDS). (512,4) bound: no spill
// (round-8's (512,6) forced VGPR=40 and spilled 1.2GB to scratch).
__global__ __launch_bounds__(512, 4) void flash_attn(
    const u16* __restrict__ Q, const u16* __restrict__ Kk,
    const u16* __restrict__ Vt, u16* __restrict__ Y) {
  __shared__ __align__(16) u16 sK[2][64 * 64];           // [key][d] swizzled
  __shared__ __align__(16) u16 sV[2][64 * 64];           // [d][key] swizzled
  const int tid = threadIdx.x, wave = tid >> 6, lane = tid & 63;
  const int l16 = lane & 15, quad = lane >> 4;
  const int sw = l16 & 7;
  const int ck0 = ((quad ^ sw) << 3);
  const int ck1 = (((quad + 4) ^ sw) << 3);
  const int rloc = tid >> 3;                 // staging row 0..63
  const int cs = (((tid & 7) ^ (rloc & 7)) << 3);
  // XCD swizzle: grid (8, 64) -> 512 blocks, 64 per XCD = 8 full head-batches
  const int id = (int)(blockIdx.y * 8 + blockIdx.x);
  const int wid = (id & 7) * 64 + (id >> 3);
  const int bh = wid >> 3;
  const int q0 = (wid & 7) * 256 + wave * 32;
  const size_t qkBase = (size_t)bh * SEQ * DH;
  const size_t vtBase = (size_t)bh * DH * SEQ;

  // V b64-read offsets (u16 units within a 64-u16 row), permuted-k B-frag
  const int q2 = quad >> 1, q1o = (quad & 1) << 2;
  const int vA0 = (((q2 + 0) ^ sw) << 3) + q1o;  // half0 h0
  const int vB0 = (((q2 + 2) ^ sw) << 3) + q1o;  // half0 h1
  const int vA1 = (((q2 + 4) ^ sw) << 3) + q1o;  // half1 h0
  const int vB1 = (((q2 + 6) ^ sw) << 3) + q1o;  // half1 h1

  // Q B-frags (pre-scaled by QSCALE): B[n=q l16][k=d quad*8+j]
  bf16x8 qf[2][2];
  for (int ms = 0; ms < 2; ++ms) {
    const u16* qrow = Q + qkBase + (size_t)(q0 + ms * 16 + l16) * DH;
    qf[ms][0] = *(const bf16x8*)(qrow + quad * 8);
    qf[ms][1] = *(const bf16x8*)(qrow + 32 + quad * 8);
  }

  bf16x8 onesf;
  for (int i = 0; i < 8; ++i) onesf[i] = (short)0x3F80;

  f32x4 o[2][4];   // [q-sub][d-sub]; lane: q=qsub*16+quad*4+r, d=dsub*16+l16
  f32x4 osum[2];
  for (int a = 0; a < 2; ++a) {
    osum[a] = (f32x4){0.f, 0.f, 0.f, 0.f};
    for (int b = 0; b < 4; ++b) o[a][b] = (f32x4){0.f, 0.f, 0.f, 0.f};
  }

  // prologue: stage key-tile 0 into buffer 0 (512 threads x 16B = full tile)
  gload_lds16(Kk + qkBase + (size_t)rloc * DH + cs, (char*)sK[0] + tid * 16);
  gload_lds16(Vt + vtBase + (size_t)rloc * SEQ + cs, (char*)sV[0] + tid * 16);
  for (int t = 0; t < 32; ++t) {
    const int cur = t & 1;
    const int kt1 = ((t + 1) & 31) * 64;
    gload_lds16(Kk + qkBase + (size_t)(kt1 + rloc) * DH + cs, (char*)sK[cur ^ 1] + tid * 16);
    gload_lds16(Vt + vtBase + (size_t)rloc * SEQ + kt1 + cs, (char*)sV[cur ^ 1] + tid * 16);
    __builtin_amdgcn_s_waitcnt(WAIT_VM2);
    __builtin_amdgcn_s_barrier();
    const u16* sk = sK[cur];
    const u16* sv = sV[cur];

    // S^T: A = K[key][d], B = Q[q][d]; lane: q=l16, keys=nt*16+quad*4+r.
    u32x4 pw[2][2];
#pragma unroll
    for (int nt = 0; nt < 4; ++nt) {
      const bf16x8 kf0 = *(const bf16x8*)&sk[(nt * 16 + l16) * 64 + ck0];
      const bf16x8 kf1 = *(const bf16x8*)&sk[(nt * 16 + l16) * 64 + ck1];
#pragma unroll
      for (int ms = 0; ms < 2; ++ms) {
        f32x4 st = (f32x4){0.f, 0.f, 0.f, 0.f};
        __builtin_amdgcn_s_setprio(1);
        st = __builtin_amdgcn_mfma_f32_16x16x32_bf16(kf0, qf[ms][0], st, 0, 0, 0);
        st = __builtin_amdgcn_mfma_f32_16x16x32_bf16(kf1, qf[ms][1], st, 0, 0, 0);
        __builtin_amdgcn_s_setprio(0);
        const u32 u0 = __builtin_bit_cast(u32, __builtin_amdgcn_exp2f(st[0]));
        const u32 u1 = __builtin_bit_cast(u32, __builtin_amdgcn_exp2f(st[1]));
        const u32 u2 = __builtin_bit_cast(u32, __builtin_amdgcn_exp2f(st[2]));
        const u32 u3 = __builtin_bit_cast(u32, __builtin_amdgcn_exp2f(st[3]));
        pw[ms][nt >> 1][(nt & 1) * 2]     = __builtin_amdgcn_perm(u1, u0, 0x07060302u);
        pw[ms][nt >> 1][(nt & 1) * 2 + 1] = __builtin_amdgcn_perm(u3, u2, 0x07060302u);
      }
    }

    // row-sums: P @ ones (k-permutation-invariant)
    __builtin_amdgcn_s_setprio(1);
#pragma unroll
    for (int ms = 0; ms < 2; ++ms) {
      osum[ms] = __builtin_amdgcn_mfma_f32_16x16x32_bf16(
          __builtin_bit_cast(bf16x8, pw[ms][0]), onesf, osum[ms], 0, 0, 0);
      osum[ms] = __builtin_amdgcn_mfma_f32_16x16x32_bf16(
          __builtin_bit_cast(bf16x8, pw[ms][1]), onesf, osum[ms], 0, 0, 0);
    }

    // PV: A = P in-register, B = Vt[d][key] with matching k-permutation
#pragma unroll
    for (int ds = 0; ds < 4; ++ds) {
      const int rb = (ds * 16 + l16) * 64;
      const bf16x8 vf0 = cat44(*(const bf16x4*)&sv[rb + vA0],
                               *(const bf16x4*)&sv[rb + vB0]);
      const bf16x8 vf1 = cat44(*(const bf16x4*)&sv[rb + vA1],
                               *(const bf16x4*)&sv[rb + vB1]);
#pragma unroll
      for (int ms = 0; ms < 2; ++ms) {
        o[ms][ds] = __builtin_amdgcn_mfma_f32_16x16x32_bf16(
            __builtin_bit_cast(bf16x8, pw[ms][0]), vf0, o[ms][ds], 0, 0, 0);
        o[ms][ds] = __builtin_amdgcn_mfma_f32_16x16x32_bf16(
            __builtin_bit_cast(bf16x8, pw[ms][1]), vf1, o[ms][ds], 0, 0, 0);
      }
    }
    __builtin_amdgcn_s_setprio(0);
    __builtin_amdgcn_s_barrier();
  }
  __builtin_amdgcn_s_waitcnt(WAIT_VM0);

  float rl[2][4];
  for (int ms = 0; ms < 2; ++ms)
    for (int r = 0; r < 4; ++r)
      rl[ms][r] = __frcp_rn(osum[ms][r]);

  // epilogue: y[b][t][h*64+d], bf16
  const int b = bh >> 4, h = bh & (NH - 1);
  for (int ms = 0; ms < 2; ++ms)
    for (int ds = 0; ds < 4; ++ds)
      for (int r = 0; r < 4; ++r) {
        const int t = q0 + ms * 16 + quad * 4 + r;
        const int d = ds * 16 + l16;
        Y[((size_t)(b * SEQ + t)) * DM + h * DH + d] = f2bf(o[ms][ds][r] * rl[ms][r]);
      }
}

extern "C" void kernel_launch(void* const* d_in, const int* in_sizes, int n_in,
                              void* d_out, int out_size, void* d_ws, size_t ws_size,
                              hipStream_t stream) {
  const float* x     = (const float*)d_in[0];   // [4,2048,1024]
  const float* Wqkv  = (const float*)d_in[1];   // [3072,1024]
  const float* Wproj = (const float*)d_in[2];   // [1024,1024]
  float* out = (float*)d_out;                   // [4,2048,1024]

  u16* xb     = (u16*)d_ws;                     // 8192*1024
  u16* bpQkv  = xb + (size_t)NTOK * DM;         // 3072*1024 (packed)
  u16* bpProj = bpQkv + (size_t)3 * DM * DM;    // 1024*1024 (packed)
  u16* Qb  = bpProj + (size_t)DM * DM;          // [B,H,T,Dh]
  u16* Kb  = Qb + (size_t)NTOK * DM;
  u16* Vtb = Kb + (size_t)NTOK * DM;            // [B,H,Dh,T]
  u16* Yb  = Vtb + (size_t)NTOK * DM;           // [B,T,C]

  {
    int n4 = NTOK * DM / 4;
    cast_kernel<<<(n4 + 255) / 256, 256, 0, stream>>>(x, xb, n4);
    pack_b<<<3 * DM * DM / 8 / 256, 256, 0, stream>>>(Wqkv, bpQkv, 3 * DM / 16);
    pack_b<<<DM * DM / 8 / 256, 256, 0, stream>>>(Wproj, bpProj, DM / 16);
  }

  // qkv = x @ Wqkv^T : M=8192, N=3072, K=1024 — 768 blocks = 3 exact rounds
  gemm_deep<0><<<dim3(3 * DM / 128, NTOK / 256), 512, 0, stream>>>(
      xb, bpQkv, 3 * DM / 16, 3 * DM, Qb, Kb, Vtb, nullptr);

  // attention: grid (T/256, B*H), 512 threads — 512 blocks
  flash_attn<<<dim3(SEQ / 256, 4 * NH), 512, 0, stream>>>(Qb, Kb, Vtb, Yb);

  // out = y @ Wproj^T : M=8192, N=1024, K=1024 — 256 blocks = 1 exact round
  gemm_deep<1><<<dim3(DM / 128, NTOK / 256), 512, 0, stream>>>(
      Yb, bpProj, DM / 16, DM, nullptr, nullptr, nullptr, out);
}

// Round 11
// 251.833 us; speedup vs baseline: 1.0566x; 1.0566x over previous
//
#include <hip/hip_runtime.h>
#include <stdint.h>
#include <stddef.h>

#define SEQ   2048
#define NH    16
#define DH    64
#define DM    1024
#define NTOK  8192   // B*T = 4*2048

typedef unsigned short u16;
typedef unsigned int u32;
typedef short bf16x8 __attribute__((ext_vector_type(8)));
typedef short bf16x4 __attribute__((ext_vector_type(4)));
typedef float f32x4  __attribute__((ext_vector_type(4)));
typedef unsigned short u16x4 __attribute__((ext_vector_type(4)));
typedef unsigned short u16x8 __attribute__((ext_vector_type(8)));
typedef unsigned int u32x4 __attribute__((ext_vector_type(4)));

// 0.125 (1/sqrt(Dh)) * log2(e): folded into Q so softmax uses bare exp2
#define QSCALE 0.18033688011112042f

// s_waitcnt immediates: vmcnt[3:0] | expcnt<<4 | lgkmcnt<<8 | vmcnt[5:4]<<14
#define WAIT_VM12 0x0F7C  // vmcnt(12)
#define WAIT_VM2  0x0F72  // vmcnt(2)
#define WAIT_VM0  0x0F70  // vmcnt(0)

// round-to-nearest-even fp32 -> bf16 bits
__device__ __forceinline__ u16 f2bf(float f) {
  union { float f; unsigned u; } v; v.f = f;
  return (u16)((v.u + 0x7FFFu + ((v.u >> 16) & 1u)) >> 16);
}

// async global->LDS, 16B per lane (dest = wave-uniform base + lane*16)
__device__ __forceinline__ void gload_lds16(const void* g, void* l) {
  __builtin_amdgcn_global_load_lds(
      (const __attribute__((address_space(1))) void*)g,
      (__attribute__((address_space(3))) void*)l, 16, 0, 0);
}

__device__ __forceinline__ bf16x8 cat44(bf16x4 a, bf16x4 b) {
  bf16x8 r;
  r[0] = a[0]; r[1] = a[1]; r[2] = a[2]; r[3] = a[3];
  r[4] = b[0]; r[5] = b[1]; r[6] = b[2]; r[7] = b[3];
  return r;
}

// Fragment-major pack body of weight W [N,K=1024] fp32 (row-major).
// Bp in 1KB blocks, block id = c*NS + s (c = k>>5 chunk, s = n>>4 subtile,
// NS = N/16). Lane l = quad*16+l16 holds the 8 bf16 W[s*16+l16][c*32+quad*8..+7]
// — exactly the per-lane MFMA B-fragment, so GEMM B loads are single
// fully-coalesced 1KB global_load_dwordx4.
__device__ __forceinline__ void pack_body(const float* __restrict__ W,
                                          u16* __restrict__ Bp, int NS, int chunk) {
  const int lane = chunk & 63, blk = chunk >> 6;
  const int c = blk / NS, s = blk % NS;
  const int n = s * 16 + (lane & 15);
  const int k0 = c * 32 + (lane >> 4) * 8;
  const float4 f0 = *(const float4*)&W[(size_t)n * DM + k0];
  const float4 f1 = *(const float4*)&W[(size_t)n * DM + k0 + 4];
  u16x8 o;
  o[0] = f2bf(f0.x); o[1] = f2bf(f0.y); o[2] = f2bf(f0.z); o[3] = f2bf(f0.w);
  o[4] = f2bf(f1.x); o[5] = f2bf(f1.y); o[6] = f2bf(f1.z); o[7] = f2bf(f1.w);
  *(u16x8*)&Bp[(size_t)chunk * 8] = o;
}

// Fused prep: x cast (blocks 0..8191) + Wqkv pack (8192..9727) + Wproj pack
// (9728..10239) in ONE launch. The three are independent memory-bound stubs;
// fusing removes two kernel boundaries (~8 µs/gap measured pipeline-level)
// and lets their memory traffic overlap.
#define CAST_BLKS (NTOK * DM / 4 / 256)        // 8192
#define PQKV_BLKS (3 * DM * DM / 8 / 256)      // 1536
#define PPRJ_BLKS (DM * DM / 8 / 256)          // 512
__global__ __launch_bounds__(256) void prep(
    const float* __restrict__ x, const float* __restrict__ Wqkv,
    const float* __restrict__ Wproj, u16* __restrict__ xb,
    u16* __restrict__ bpQkv, u16* __restrict__ bpProj) {
  const int bid = blockIdx.x;
  if (bid < CAST_BLKS) {
    const int i = bid * 256 + threadIdx.x;
    const float4 f = ((const float4*)x)[i];
    u16x4 o;
    o.x = f2bf(f.x); o.y = f2bf(f.y); o.z = f2bf(f.z); o.w = f2bf(f.w);
    ((u16x4*)xb)[i] = o;
  } else if (bid < CAST_BLKS + PQKV_BLKS) {
    pack_body(Wqkv, bpQkv, 3 * DM / 16, (bid - CAST_BLKS) * 256 + threadIdx.x);
  } else {
    pack_body(Wproj, bpProj, DM / 16,
              (bid - CAST_BLKS - PQKV_BLKS) * 256 + threadIdx.x);
  }
}

// C[M,N] = A[M,1024] * B[N,1024]^T, B pre-packed fragment-major (see pack_body).
// 128x128 tile, BK=64, 4 waves (2x2 of 64x64). A is LDS-staged (dbuf,
// XOR-swizzled, split-barrier); B streams global->VGPR with register double
// buffer = one full K-iter of prefetch distance (vmcnt(12)).
// XCD-chunked blockIdx swizzle (T1). [round-6 verified best configuration;
// rounds 3/4/7/10 restructures (4-phase, half-buffer, 32x32 MFMA, tri-buffer
// deep pipeline) all measured neutral-to-worse — this structure is final.]
template <int EPI>
__global__ __launch_bounds__(256) void gemm_flat(
    const u16* __restrict__ A, const u16* __restrict__ Bp, int NS, int N_,
    u16* __restrict__ Qo, u16* __restrict__ Ko, u16* __restrict__ Vto,
    float* __restrict__ Co) {
  __shared__ __align__(16) u16 sA[2][128 * 64];
  const int tid = threadIdx.x;
  const int wave = tid >> 6, lane = tid & 63;
  const int l16 = lane & 15, quad = lane >> 4;
  const int sw = l16 & 7;
  const int wm = (wave >> 1) * 64, wn = (wave & 1) * 64;
  // XCD swizzle: bijective for nwg % 8 == 0 (1536 and 512 here)
  const int nbx = (int)gridDim.x;
  const int id = (int)(blockIdx.y * nbx + blockIdx.x);
  const int cpx = (int)(gridDim.x * gridDim.y) >> 3;
  const int wid = (id & 7) * cpx + (id >> 3);
  const int row0 = (wid / nbx) * 128, col0 = (wid % nbx) * 128;
  const int ck0 = ((quad ^ sw) << 3);
  const int ck1 = (((quad + 4) ^ sw) << 3);
  const int scol = (col0 + wn) >> 4;            // n-subtile base for this wave
  const u16* bpw = Bp + (size_t)lane * 8;       // + block*512 u16

  f32x4 acc[4][4];
  for (int a = 0; a < 4; ++a)
    for (int b = 0; b < 4; ++b) acc[a][b] = (f32x4){0.f, 0.f, 0.f, 0.f};

  bf16x8 bfr[2][2][4];  // [parity][kk][i]

  // prologue: stage A k-tile 0 -> sA[0]; load B frags c=0,1 -> bfr[0]
  for (int j = 0; j < 4; ++j) {
    const int li = j * 256 + tid;
    const int r = li >> 3;
    const int cs = (((li & 7) ^ (r & 7)) << 3);
    gload_lds16(A + (size_t)(row0 + r) * DM + cs, (char*)sA[0] + li * 16);
  }
  for (int kk = 0; kk < 2; ++kk) {
    const u16* bb = bpw + ((size_t)kk * NS + scol) * 512;
    for (int i = 0; i < 4; ++i)
      bfr[0][kk][i] = *(const bf16x8*)(bb + i * 512);
  }

#pragma unroll 2
  for (int t = 0; t < 16; ++t) {
    const int cur = t & 1;
    const int tn = (t + 1) & 15;                // wrap: last iter re-stages k=0
    const int k1 = tn << 6;
    for (int j = 0; j < 4; ++j) {
      const int li = j * 256 + tid;
      const int r = li >> 3;
      const int cs = (((li & 7) ^ (r & 7)) << 3);
      gload_lds16(A + (size_t)(row0 + r) * DM + k1 + cs, (char*)sA[cur ^ 1] + li * 16);
    }
    for (int kk = 0; kk < 2; ++kk) {
      const u16* bb = bpw + ((size_t)(tn * 2 + kk) * NS + scol) * 512;
      for (int i = 0; i < 4; ++i)
        bfr[cur ^ 1][kk][i] = *(const bf16x8*)(bb + i * 512);
    }
    __builtin_amdgcn_s_waitcnt(WAIT_VM12);  // A(t)+B(t) done; 12 newer in flight
    __builtin_amdgcn_s_barrier();
    const u16* sa = sA[cur];
    for (int kk = 0; kk < 2; ++kk) {
      const int cko = kk ? ck1 : ck0;
      bf16x8 af[4];
      for (int i = 0; i < 4; ++i)
        af[i] = *(const bf16x8*)&sa[(wm + i * 16 + l16) * 64 + cko];
      for (int mi = 0; mi < 4; ++mi)
        for (int ni = 0; ni < 4; ++ni)
          acc[mi][ni] = __builtin_amdgcn_mfma_f32_16x16x32_bf16(
              af[mi], bfr[cur][kk][ni], acc[mi][ni], 0, 0, 0);
    }
    __builtin_amdgcn_s_barrier();
  }
  __builtin_amdgcn_s_waitcnt(WAIT_VM0);  // drain dangling wrap stage before exit

  // C/D layout: col = lane&15, row = quad*4 + reg
  if (EPI == 0) {
    const int which = col0 >> 10;  // 0:Q 1:K 2:V — uniform per block
    for (int mi = 0; mi < 4; ++mi)
      for (int ni = 0; ni < 4; ++ni) {
        const int rowb = row0 + wm + mi * 16 + quad * 4;
        const int col = col0 + wn + ni * 16 + l16;
        const int b = rowb >> 11, t = rowb & (SEQ - 1);
        const int c = col & (DM - 1);
        const int h = c >> 6, d = c & 63;
        const size_t bh = (size_t)b * NH + h;
        if (which == 2) {
          u16x4 pk;
          pk.x = f2bf(acc[mi][ni][0]); pk.y = f2bf(acc[mi][ni][1]);
          pk.z = f2bf(acc[mi][ni][2]); pk.w = f2bf(acc[mi][ni][3]);
          *(u16x4*)&Vto[(bh * DH + d) * SEQ + t] = pk;
        } else {
          for (int r = 0; r < 4; ++r) {
            const float v = acc[mi][ni][r];
            if (which == 0) Qo[(bh * SEQ + t + r) * DH + d] = f2bf(v * QSCALE);
            else            Ko[(bh * SEQ + t + r) * DH + d] = f2bf(v);
          }
        }
      }
  } else {
    for (int mi = 0; mi < 4; ++mi)
      for (int ni = 0; ni < 4; ++ni)
        for (int r = 0; r < 4; ++r) {
          const int row = row0 + wm + mi * 16 + quad * 4 + r;
          const int col = col0 + wn + ni * 16 + l16;
          Co[(size_t)row * N_ + col] = acc[mi][ni][r];
        }
  }
}

// Flash attention, non-causal, fixed max=0. 256 q/block, 8 waves x 32 q/wave
// (512 threads), dbuf K/V staging, S^T = K.Q^T, P @ ones row-sums, raw
// v_exp_f32, setprio(1) around MFMA clusters (T5). Grid: (T/256, B*H).
// XCD-chunked swizzle (round-6: FETCH 143 -> 25 MB, K/V L2-resident).
// In-register P via permuted-k PV fragments (round-9: equal perf to sP at the
// grid-capped 2 blocks/CU, fewer LDS ops, 32KB LDS). (512,4) bound: no spill
// (round-8's (512,6) forced VGPR=40 and spilled 1.2GB to scratch).
// Closed at ~82 µs: LDS reads already ~38 TB/s (55% of 69 TB/s ceiling) and
// issue-sum 84%; finer q-split would double LDS reads/q -> LDS-bound >=90 µs.
__global__ __launch_bounds__(512, 4) void flash_attn(
    const u16* __restrict__ Q, const u16* __restrict__ Kk,
    const u16* __restrict__ Vt, u16* __restrict__ Y) {
  __shared__ __align__(16) u16 sK[2][64 * 64];           // [key][d] swizzled
  __shared__ __align__(16) u16 sV[2][64 * 64];           // [d][key] swizzled
  const int tid = threadIdx.x, wave = tid >> 6, lane = tid & 63;
  const int l16 = lane & 15, quad = lane >> 4;
  const int sw = l16 & 7;
  const int ck0 = ((quad ^ sw) << 3);
  const int ck1 = (((quad + 4) ^ sw) << 3);
  const int rloc = tid >> 3;                 // staging row 0..63
  const int cs = (((tid & 7) ^ (rloc & 7)) << 3);
  // XCD swizzle: grid (8, 64) -> 512 blocks, 64 per XCD = 8 full head-batches
  const int id = (int)(blockIdx.y * 8 + blockIdx.x);
  const int wid = (id & 7) * 64 + (id >> 3);
  const int bh = wid >> 3;
  const int q0 = (wid & 7) * 256 + wave * 32;
  const size_t qkBase = (size_t)bh * SEQ * DH;
  const size_t vtBase = (size_t)bh * DH * SEQ;

  // V b64-read offsets (u16 units within a 64-u16 row), permuted-k B-frag
  const int q2 = quad >> 1, q1o = (quad & 1) << 2;
  const int vA0 = (((q2 + 0) ^ sw) << 3) + q1o;  // half0 h0
  const int vB0 = (((q2 + 2) ^ sw) << 3) + q1o;  // half0 h1
  const int vA1 = (((q2 + 4) ^ sw) << 3) + q1o;  // half1 h0
  const int vB1 = (((q2 + 6) ^ sw) << 3) + q1o;  // half1 h1

  // Q B-frags (pre-scaled by QSCALE): B[n=q l16][k=d quad*8+j]
  bf16x8 qf[2][2];
  for (int ms = 0; ms < 2; ++ms) {
    const u16* qrow = Q + qkBase + (size_t)(q0 + ms * 16 + l16) * DH;
    qf[ms][0] = *(const bf16x8*)(qrow + quad * 8);
    qf[ms][1] = *(const bf16x8*)(qrow + 32 + quad * 8);
  }

  bf16x8 onesf;
  for (int i = 0; i < 8; ++i) onesf[i] = (short)0x3F80;

  f32x4 o[2][4];   // [q-sub][d-sub]; lane: q=qsub*16+quad*4+r, d=dsub*16+l16
  f32x4 osum[2];
  for (int a = 0; a < 2; ++a) {
    osum[a] = (f32x4){0.f, 0.f, 0.f, 0.f};
    for (int b = 0; b < 4; ++b) o[a][b] = (f32x4){0.f, 0.f, 0.f, 0.f};
  }

  // prologue: stage key-tile 0 into buffer 0 (512 threads x 16B = full tile)
  gload_lds16(Kk + qkBase + (size_t)rloc * DH + cs, (char*)sK[0] + tid * 16);
  gload_lds16(Vt + vtBase + (size_t)rloc * SEQ + cs, (char*)sV[0] + tid * 16);
  for (int t = 0; t < 32; ++t) {
    const int cur = t & 1;
    const int kt1 = ((t + 1) & 31) * 64;
    gload_lds16(Kk + qkBase + (size_t)(kt1 + rloc) * DH + cs, (char*)sK[cur ^ 1] + tid * 16);
    gload_lds16(Vt + vtBase + (size_t)rloc * SEQ + kt1 + cs, (char*)sV[cur ^ 1] + tid * 16);
    __builtin_amdgcn_s_waitcnt(WAIT_VM2);
    __builtin_amdgcn_s_barrier();
    const u16* sk = sK[cur];
    const u16* sv = sV[cur];

    // S^T: A = K[key][d], B = Q[q][d]; lane: q=l16, keys=nt*16+quad*4+r.
    u32x4 pw[2][2];
#pragma unroll
    for (int nt = 0; nt < 4; ++nt) {
      const bf16x8 kf0 = *(const bf16x8*)&sk[(nt * 16 + l16) * 64 + ck0];
      const bf16x8 kf1 = *(const bf16x8*)&sk[(nt * 16 + l16) * 64 + ck1];
#pragma unroll
      for (int ms = 0; ms < 2; ++ms) {
        f32x4 st = (f32x4){0.f, 0.f, 0.f, 0.f};
        __builtin_amdgcn_s_setprio(1);
        st = __builtin_amdgcn_mfma_f32_16x16x32_bf16(kf0, qf[ms][0], st, 0, 0, 0);
        st = __builtin_amdgcn_mfma_f32_16x16x32_bf16(kf1, qf[ms][1], st, 0, 0, 0);
        __builtin_amdgcn_s_setprio(0);
        const u32 u0 = __builtin_bit_cast(u32, __builtin_amdgcn_exp2f(st[0]));
        const u32 u1 = __builtin_bit_cast(u32, __builtin_amdgcn_exp2f(st[1]));
        const u32 u2 = __builtin_bit_cast(u32, __builtin_amdgcn_exp2f(st[2]));
        const u32 u3 = __builtin_bit_cast(u32, __builtin_amdgcn_exp2f(st[3]));
        pw[ms][nt >> 1][(nt & 1) * 2]     = __builtin_amdgcn_perm(u1, u0, 0x07060302u);
        pw[ms][nt >> 1][(nt & 1) * 2 + 1] = __builtin_amdgcn_perm(u3, u2, 0x07060302u);
      }
    }

    // row-sums: P @ ones (k-permutation-invariant)
    __builtin_amdgcn_s_setprio(1);
#pragma unroll
    for (int ms = 0; ms < 2; ++ms) {
      osum[ms] = __builtin_amdgcn_mfma_f32_16x16x32_bf16(
          __builtin_bit_cast(bf16x8, pw[ms][0]), onesf, osum[ms], 0, 0, 0);
      osum[ms] = __builtin_amdgcn_mfma_f32_16x16x32_bf16(
          __builtin_bit_cast(bf16x8, pw[ms][1]), onesf, osum[ms], 0, 0, 0);
    }

    // PV: A = P in-register, B = Vt[d][key] with matching k-permutation
#pragma unroll
    for (int ds = 0; ds < 4; ++ds) {
      const int rb = (ds * 16 + l16) * 64;
      const bf16x8 vf0 = cat44(*(const bf16x4*)&sv[rb + vA0],
                               *(const bf16x4*)&sv[rb + vB0]);
      const bf16x8 vf1 = cat44(*(const bf16x4*)&sv[rb + vA1],
                               *(const bf16x4*)&sv[rb + vB1]);
#pragma unroll
      for (int ms = 0; ms < 2; ++ms) {
        o[ms][ds] = __builtin_amdgcn_mfma_f32_16x16x32_bf16(
            __builtin_bit_cast(bf16x8, pw[ms][0]), vf0, o[ms][ds], 0, 0, 0);
        o[ms][ds] = __builtin_amdgcn_mfma_f32_16x16x32_bf16(
            __builtin_bit_cast(bf16x8, pw[ms][1]), vf1, o[ms][ds], 0, 0, 0);
      }
    }
    __builtin_amdgcn_s_setprio(0);
    __builtin_amdgcn_s_barrier();
  }
  __builtin_amdgcn_s_waitcnt(WAIT_VM0);

  float rl[2][4];
  for (int ms = 0; ms < 2; ++ms)
    for (int r = 0; r < 4; ++r)
      rl[ms][r] = __frcp_rn(osum[ms][r]);

  // epilogue: y[b][t][h*64+d], bf16
  const int b = bh >> 4, h = bh & (NH - 1);
  for (int ms = 0; ms < 2; ++ms)
    for (int ds = 0; ds < 4; ++ds)
      for (int r = 0; r < 4; ++r) {
        const int t = q0 + ms * 16 + quad * 4 + r;
        const int d = ds * 16 + l16;
        Y[((size_t)(b * SEQ + t)) * DM + h * DH + d] = f2bf(o[ms][ds][r] * rl[ms][r]);
      }
}

extern "C" void kernel_launch(void* const* d_in, const int* in_sizes, int n_in,
                              void* d_out, int out_size, void* d_ws, size_t ws_size,
                              hipStream_t stream) {
  const float* x     = (const float*)d_in[0];   // [4,2048,1024]
  const float* Wqkv  = (const float*)d_in[1];   // [3072,1024]
  const float* Wproj = (const float*)d_in[2];   // [1024,1024]
  float* out = (float*)d_out;                   // [4,2048,1024]

  u16* xb     = (u16*)d_ws;                     // 8192*1024
  u16* bpQkv  = xb + (size_t)NTOK * DM;         // 3072*1024 (packed)
  u16* bpProj = bpQkv + (size_t)3 * DM * DM;    // 1024*1024 (packed)
  u16* Qb  = bpProj + (size_t)DM * DM;          // [B,H,T,Dh]
  u16* Kb  = Qb + (size_t)NTOK * DM;
  u16* Vtb = Kb + (size_t)NTOK * DM;            // [B,H,Dh,T]
  u16* Yb  = Vtb + (size_t)NTOK * DM;           // [B,T,C]

  // fused prep: cast + both weight packs in one launch
  prep<<<CAST_BLKS + PQKV_BLKS + PPRJ_BLKS, 256, 0, stream>>>(
      x, Wqkv, Wproj, xb, bpQkv, bpProj);

  // qkv = x @ Wqkv^T : M=8192, N=3072, K=1024 — 1536 blocks (8 | nwg)
  gemm_flat<0><<<dim3(3 * DM / 128, NTOK / 128), 256, 0, stream>>>(
      xb, bpQkv, 3 * DM / 16, 3 * DM, Qb, Kb, Vtb, nullptr);

  // attention: grid (T/256, B*H), 512 threads — 512 blocks (8 | nwg)
  flash_attn<<<dim3(SEQ / 256, 4 * NH), 512, 0, stream>>>(Qb, Kb, Vtb, Yb);

  // out = y @ Wproj^T : M=8192, N=1024, K=1024 — 512 blocks (8 | nwg)
  gemm_flat<1><<<dim3(DM / 128, NTOK / 128), 256, 0, stream>>>(
      Yb, bpProj, DM / 16, DM, nullptr, nullptr, nullptr, out);
}